// Round 1
// baseline (1130.761 us; speedup 1.0000x reference)
//
#include <hip/hip_runtime.h>

#define IN_F 1024
#define NVOC 32000
#define NTOK 8192
#define BM 128
#define BN 128
#define BK 64
#define NT (NVOC / BN)   /* 250 n-tiles */
#define MT (NTOK / BM)   /* 64 m-tiles  */
#define SMOOTH 0.1f

typedef __attribute__((ext_vector_type(8))) short short8;   // 8 bf16 = 4 VGPRs
typedef __attribute__((ext_vector_type(4))) float f32x4;    // MFMA acc
typedef unsigned int u32;

__device__ inline unsigned short f2bf(float f) {
  // round-to-nearest-even f32 -> bf16
  u32 u = __float_as_uint(f);
  return (unsigned short)((u + 0x7fffu + ((u >> 16) & 1u)) >> 16);
}

__device__ inline void gload_lds16(const void* g, void* l) {
  // async global->LDS, 16B per lane; LDS dest = wave-uniform base + lane*16
  __builtin_amdgcn_global_load_lds(
      (const __attribute__((address_space(1))) u32*)g,
      (__attribute__((address_space(3))) u32*)l, 16, 0, 0);
}

// ---------------------------------------------------------------------------
// Normalize target indices: harness may stage int64 (lower/upper word pairs)
// or int32. Detect: if all "upper words" of the first 4096 entries are zero,
// it's int64 (targets < 2^31). Random int32 targets make that probability ~0.
// ---------------------------------------------------------------------------
__global__ void fix_target(const int* __restrict__ traw, int* __restrict__ tgtidx) {
  __shared__ int flag;
  if (threadIdx.x == 0) flag = 0;
  __syncthreads();
  int any = 0;
  for (int i = threadIdx.x; i < NTOK / 2; i += 256) any |= (traw[2 * i + 1] != 0);
  if (any) atomicOr(&flag, 1);
  __syncthreads();
  const int is64 = (flag == 0);
  for (int i = threadIdx.x; i < NTOK; i += 256)
    tgtidx[i] = is64 ? traw[2 * i] : traw[i];
}

// ---------------------------------------------------------------------------
// fp32 -> bf16 bulk convert (float4 in, ushort4 out)
// ---------------------------------------------------------------------------
__global__ void convert_bf16(const float4* __restrict__ in, ushort4* __restrict__ out, int n4) {
  int i = blockIdx.x * blockDim.x + threadIdx.x;
  const int stride = gridDim.x * blockDim.x;
  for (; i < n4; i += stride) {
    const float4 v = in[i];
    ushort4 o;
    o.x = f2bf(v.x); o.y = f2bf(v.y); o.z = f2bf(v.z); o.w = f2bf(v.w);
    out[i] = o;
  }
}

// ---------------------------------------------------------------------------
// K1: 128x128 logits tile via bf16 MFMA, fused row-wise (max, sumexp, sumlog)
// partials + target-logit pick. LDS A/B tiles are [row][8 chunks of 16B] with
// chunk position XOR-swizzled by (row&7) so both global_load_lds staging
// (contiguous, unpadded) and ds_read_b128 frag reads stay bank-balanced.
// ---------------------------------------------------------------------------
template <bool PRECONV>
__global__ __launch_bounds__(256) void gemm_partials(
    const void* __restrict__ Xv, const void* __restrict__ Wv,
    const float* __restrict__ bias, const int* __restrict__ tgtidx,
    float* __restrict__ pmax, float* __restrict__ psum,
    float* __restrict__ pslog, float* __restrict__ tgtlogit) {
  __shared__ char smem[35328];
  char* As = smem;                    // [128][128B] bf16 A tile (16 KB)
  char* Bs = smem + 16384;            // [128][128B] bf16 B tile (16 KB)
  float* Cbuf = (float*)smem;         // epilogue: [128 cols][68] fp32 (aliases A/B)
  float* biasS = (float*)(smem + 34816);  // [128] bias

  const int tid = threadIdx.x;
  const int wave = tid >> 6, lane = tid & 63;
  const int wm = wave & 1, wn = wave >> 1;        // 2x2 wave grid, each 64x64
  const int quad = lane >> 4, l16 = lane & 15;
  const int n0 = blockIdx.x * BN, m0 = blockIdx.y * BM;

  if (tid < BN) biasS[tid] = bias[n0 + tid];

  const f32x4 zero = {0.f, 0.f, 0.f, 0.f};
  f32x4 acc[4][4];
#pragma unroll
  for (int i = 0; i < 4; ++i)
#pragma unroll
    for (int j = 0; j < 4; ++j) acc[i][j] = zero;

  for (int kt = 0; kt < IN_F / BK; ++kt) {
    if (PRECONV) {
      const unsigned short* Xb = (const unsigned short*)Xv;
      const unsigned short* Wb = (const unsigned short*)Wv;
      __syncthreads();  // previous compute done reading LDS
      const int lr = lane >> 3, lc = lane & 7;
#pragma unroll
      for (int i = 0; i < 4; ++i) {
        const int R0 = wave * 32 + i * 8;          // wave-uniform row base
        const int row = R0 + lr;
        const int c = lc ^ (row & 7);              // fetch the chunk that lands at slot lc
        gload_lds16(Xb + (size_t)(m0 + row) * IN_F + kt * BK + c * 8, As + R0 * 128);
        gload_lds16(Wb + (size_t)(n0 + row) * IN_F + kt * BK + c * 8, Bs + R0 * 128);
      }
      __syncthreads();  // compiler drains vmcnt(0) before barrier
    } else {
      const float* X = (const float*)Xv;
      const float* W = (const float*)Wv;
      const int row = tid >> 1, hs = tid & 1;
      const float4* gA = (const float4*)(X + (size_t)(m0 + row) * IN_F + kt * BK + hs * 32);
      const float4* gB = (const float4*)(W + (size_t)(n0 + row) * IN_F + kt * BK + hs * 32);
      float4 a4[8], b4[8];
#pragma unroll
      for (int k = 0; k < 8; ++k) a4[k] = gA[k];
#pragma unroll
      for (int k = 0; k < 8; ++k) b4[k] = gB[k];
      __syncthreads();
#pragma unroll
      for (int cl = 0; cl < 4; ++cl) {
        const float4 x0 = a4[2 * cl], x1 = a4[2 * cl + 1];
        const float4 y0 = b4[2 * cl], y1 = b4[2 * cl + 1];
        short8 sa, sb;
        sa[0] = (short)f2bf(x0.x); sa[1] = (short)f2bf(x0.y);
        sa[2] = (short)f2bf(x0.z); sa[3] = (short)f2bf(x0.w);
        sa[4] = (short)f2bf(x1.x); sa[5] = (short)f2bf(x1.y);
        sa[6] = (short)f2bf(x1.z); sa[7] = (short)f2bf(x1.w);
        sb[0] = (short)f2bf(y0.x); sb[1] = (short)f2bf(y0.y);
        sb[2] = (short)f2bf(y0.z); sb[3] = (short)f2bf(y0.w);
        sb[4] = (short)f2bf(y1.x); sb[5] = (short)f2bf(y1.y);
        sb[6] = (short)f2bf(y1.z); sb[7] = (short)f2bf(y1.w);
        const int c = hs * 4 + cl;
        const int p = (c ^ (row & 7)) << 4;
        *(short8*)(As + row * 128 + p) = sa;
        *(short8*)(Bs + row * 128 + p) = sb;
      }
      __syncthreads();
    }

    // ---- MFMA: 2 k-steps of 16x16x32, 4x4 tiles per wave -----------------
#pragma unroll
    for (int kk = 0; kk < 2; ++kk) {
      short8 af[4], bfv[4];
#pragma unroll
      for (int t = 0; t < 4; ++t) {
        const int ar = wm * 64 + t * 16 + l16;   // A row (token-local)
        af[t] = *(const short8*)(As + ar * 128 + ((((kk << 2) + quad) ^ (ar & 7)) << 4));
        const int br = wn * 64 + t * 16 + l16;   // W row (= logit column)
        bfv[t] = *(const short8*)(Bs + br * 128 + ((((kk << 2) + quad) ^ (br & 7)) << 4));
      }
#pragma unroll
      for (int i = 0; i < 4; ++i)
#pragma unroll
        for (int j = 0; j < 4; ++j)
          acc[i][j] = __builtin_amdgcn_mfma_f32_16x16x32_bf16(af[i], bfv[j], acc[i][j], 0, 0, 0);
    }
  }

  // ---- Epilogue: two 64-row halves through LDS (column-major, stride 68) --
  // C/D layout: col = lane&15, row = quad*4 + reg  [measured m89/m91]
  const int r = tid >> 2, sub = tid & 3;  // 4 threads per row, 32 cols each
  for (int h = 0; h < 2; ++h) {
    __syncthreads();  // previous phase done with LDS
    if (wm == h) {
#pragma unroll
      for (int i = 0; i < 4; ++i) {
        const int R = i * 16 + quad * 4;  // local row base (0..63)
#pragma unroll
        for (int j = 0; j < 4; ++j) {
          const int cl = wn * 64 + j * 16 + l16;  // col 0..127
          const float bv = biasS[cl];
          f32x4 v = acc[i][j];
          v[0] += bv; v[1] += bv; v[2] += bv; v[3] += bv;
          *(f32x4*)(Cbuf + cl * 68 + R) = v;  // ds_write_b128, 16B aligned
        }
      }
    }
    __syncthreads();
    float mx = -3.4e38f;
#pragma unroll 8
    for (int i2 = 0; i2 < 32; ++i2)
      mx = fmaxf(mx, Cbuf[(sub * 32 + i2) * 68 + r]);
    mx = fmaxf(mx, __shfl_xor(mx, 1));
    mx = fmaxf(mx, __shfl_xor(mx, 2));
    float se = 0.f, sl = 0.f;
#pragma unroll 8
    for (int i2 = 0; i2 < 32; ++i2) {
      const float v = Cbuf[(sub * 32 + i2) * 68 + r];
      se += __expf(v - mx);
      sl += v;
    }
    se += __shfl_xor(se, 1); se += __shfl_xor(se, 2);
    sl += __shfl_xor(sl, 1); sl += __shfl_xor(sl, 2);
    if (sub == 0) {
      const int m = m0 + h * 64 + r;
      const size_t idx = (size_t)m * NT + blockIdx.x;
      pmax[idx] = mx;
      psum[idx] = se;
      pslog[idx] = sl;
      const int t = tgtidx[m];
      const int ct = t - n0;
      if (ct >= 0 && ct < BN) tgtlogit[m] = Cbuf[ct * 68 + r];
    }
  }
}

// ---------------------------------------------------------------------------
// K2: per-token logsumexp merge over 250 tile-partials (1 wave per token)
// ---------------------------------------------------------------------------
__global__ __launch_bounds__(256) void combine(
    const float* __restrict__ pmax, const float* __restrict__ psum,
    const float* __restrict__ pslog, const float* __restrict__ tgtlogit,
    const int* __restrict__ tgtidx, float* __restrict__ pertok) {
  const int token = blockIdx.x * 4 + (threadIdx.x >> 6);
  const int lane = threadIdx.x & 63;
  float m = -3.4e38f, se = 0.f, sl = 0.f;
  for (int l = lane; l < NT; l += 64) {
    const size_t idx = (size_t)token * NT + l;
    const float om = pmax[idx], os = psum[idx];
    const float M = fmaxf(m, om);
    se = se * __expf(m - M) + os * __expf(om - M);
    m = M;
    sl += pslog[idx];
  }
#pragma unroll
  for (int d = 1; d < 64; d <<= 1) {
    const float om = __shfl_xor(m, d), os = __shfl_xor(se, d);
    const float M = fmaxf(m, om);
    se = se * __expf(m - M) + os * __expf(om - M);
    m = M;
    sl += __shfl_xor(sl, d);
  }
  if (lane == 0) {
    const int t = tgtidx[token];
    const float logZ = m + logf(se);
    const float nll = logZ - tgtlogit[token];
    const float smooth = (float)NVOC * logZ - sl;
    const float pt = (1.f - SMOOTH) * nll + (SMOOTH / (float)NVOC) * smooth;
    pertok[token] = (t != 0) ? pt : 0.f;
  }
}

// ---------------------------------------------------------------------------
// K3: sum 8192 per-token losses -> d_out[0]
// ---------------------------------------------------------------------------
__global__ __launch_bounds__(256) void finalsum(const float* __restrict__ pertok,
                                                float* __restrict__ out) {
  const int tid = threadIdx.x;
  float s = 0.f;
  for (int i = tid; i < NTOK; i += 256) s += pertok[i];
#pragma unroll
  for (int d = 1; d < 64; d <<= 1) s += __shfl_xor(s, d);
  __shared__ float wsum[4];
  if ((tid & 63) == 0) wsum[tid >> 6] = s;
  __syncthreads();
  if (tid == 0) out[0] = wsum[0] + wsum[1] + wsum[2] + wsum[3];
}

extern "C" void kernel_launch(void* const* d_in, const int* in_sizes, int n_in,
                              void* d_out, int out_size, void* d_ws, size_t ws_size,
                              hipStream_t stream) {
  (void)in_sizes; (void)n_in; (void)out_size;
  const float* x = (const float*)d_in[0];
  const int* traw = (const int*)d_in[1];
  const float* w = (const float*)d_in[2];
  const float* bias = (const float*)d_in[3];

  // workspace layout (floats/ints are 4B; bf16 region 16B-aligned)
  char* ws = (char*)d_ws;
  float* pmax = (float*)ws;
  float* psum = pmax + (size_t)NTOK * NT;
  float* pslog = psum + (size_t)NTOK * NT;
  float* tgtlogit = pslog + (size_t)NTOK * NT;
  float* pertok = tgtlogit + NTOK;
  int* tgtidx = (int*)(pertok + NTOK);
  char* bfbase = (char*)(tgtidx + NTOK);
  const size_t base_need = (size_t)(bfbase - ws);
  const size_t bf_need = (size_t)NTOK * IN_F * 2 + (size_t)NVOC * IN_F * 2;
  const bool preconv = ws_size >= base_need + bf_need;

  fix_target<<<1, 256, 0, stream>>>(traw, tgtidx);

  const dim3 grid(NT, MT);
  if (preconv) {
    unsigned short* xb = (unsigned short*)bfbase;
    unsigned short* wb = xb + (size_t)NTOK * IN_F;
    convert_bf16<<<4096, 256, 0, stream>>>((const float4*)x, (ushort4*)xb, NTOK * IN_F / 4);
    convert_bf16<<<8192, 256, 0, stream>>>((const float4*)w, (ushort4*)wb, NVOC * IN_F / 4);
    gemm_partials<true><<<grid, 256, 0, stream>>>(xb, wb, bias, tgtidx, pmax, psum, pslog, tgtlogit);
  } else {
    gemm_partials<false><<<grid, 256, 0, stream>>>(x, w, bias, tgtidx, pmax, psum, pslog, tgtlogit);
  }
  combine<<<NTOK / 4, 256, 0, stream>>>(pmax, psum, pslog, tgtlogit, tgtidx, pertok);
  finalsum<<<1, 256, 0, stream>>>(pertok, (float*)d_out);
}